// Round 6
// baseline (527.323 us; speedup 1.0000x reference)
//
#include <hip/hip_runtime.h>
#include <math.h>

typedef _Float16 f16;
typedef _Float16 f16x2 __attribute__((ext_vector_type(2)));
typedef _Float16 f16x4 __attribute__((ext_vector_type(4)));
typedef _Float16 f16x8 __attribute__((ext_vector_type(8)));
typedef float f32x4 __attribute__((ext_vector_type(4)));

#define K_HID 2048
#define N_SEQ 4096
#define N_BATCH 2
#define M_ROWS 8192   // B*S

// async global->LDS, 16B per lane. LDS dest must be WAVE-UNIFORM base;
// HW writes lane i at base + i*16 (lane-contiguous, no padding allowed).
__device__ __forceinline__ void gl2lds16(const f16* g, f16* l) {
  auto gp = (const __attribute__((address_space(1))) unsigned*)(unsigned long long)(uintptr_t)g;
  auto lp = (__attribute__((address_space(3))) unsigned*)(unsigned)(uintptr_t)l;
  __builtin_amdgcn_global_load_lds(gp, lp, 16, 0, 0);
}

// ---------------- f32 -> f16 conversion (8 elems/thread) ----------------
__global__ __launch_bounds__(256) void cvt_f32_to_f16(const float* __restrict__ x,
                                                      f16* __restrict__ y, int n) {
  int i = (blockIdx.x * 256 + threadIdx.x) * 8;
  if (i >= n) return;
  float4 a = *(const float4*)(x + i);
  float4 b = *(const float4*)(x + i + 4);
  f16x8 o;
  o[0] = (f16)a.x; o[1] = (f16)a.y; o[2] = (f16)a.z; o[3] = (f16)a.w;
  o[4] = (f16)b.x; o[5] = (f16)b.y; o[6] = (f16)b.z; o[7] = (f16)b.w;
  *(f16x8*)(y + i) = o;
}

// -------- weight transpose+convert: W[K][N] f32 -> Wt[N][K] f16 ----------
__global__ __launch_bounds__(256) void transpose_cvt(const float* __restrict__ W0,
                                                     const float* __restrict__ W1,
                                                     const float* __restrict__ W2,
                                                     const float* __restrict__ W3,
                                                     f16* __restrict__ WT) {
  const float* W = (blockIdx.z == 0) ? W0 : (blockIdx.z == 1) ? W1
                 : (blockIdx.z == 2) ? W2 : W3;
  f16* Wt = WT + (size_t)blockIdx.z * K_HID * K_HID;
  __shared__ float tile[32][33];
  int bx = blockIdx.x * 32;   // n base
  int by = blockIdx.y * 32;   // k base
  int x = threadIdx.x & 31;
  int y = threadIdx.x >> 5;   // 0..7
  for (int i = 0; i < 32; i += 8)
    tile[y + i][x] = W[(size_t)(by + y + i) * K_HID + bx + x];
  __syncthreads();
  for (int i = 0; i < 32; i += 8)
    Wt[(size_t)(bx + y + i) * K_HID + by + x] = (f16)tile[x][y + i];
}

// ---------------- GEMM: C[M][N] = A[M][K] * Bt[N][K]^T ----------------
// (round-2 winner, re-reverted after round-5's 4-phase regression: 200 us
// QKV, MfmaUtil 46.7%, 0 bank conflicts. Round-5 lesson: 8 barriers/K-tile
// costs more than finer interleave gains — keep 2 barriers/K-tile.)
// 256x256 tile, BK=64, 512 threads = 8 waves (2M x 4N), per-wave 128x64 out.
// Double-buffered 128 KiB LDS; counted-vmcnt pipeline: stage next K-tile's A
// before the barrier, wait vmcnt(4) so those loads stay in flight ACROSS the
// raw s_barrier; stage B mid-iteration under the first MFMA half. setprio(1)
// wraps the MFMA clusters. LDS linear (gl2lds) with pre-swizzled global
// source chunk^=(row&7): 128B row stride + 3-bit XOR -> conflict-free b128.
template <typename OutT>
__global__ __launch_bounds__(512, 2) void gemm_bt(const f16* __restrict__ A,
                                                  const f16* __restrict__ BtBase,
                                                  OutT* __restrict__ CBase,
                                                  int M, int N, int Kd,
                                                  size_t bzStride, size_t czStride) {
  const f16* Bt = BtBase + bzStride * blockIdx.z;
  OutT* C = CBase + czStride * blockIdx.z;
  __shared__ f16 sA[2][256 * 64];   // 32 KiB per buffer
  __shared__ f16 sB[2][256 * 64];
  int tid = threadIdx.x;
  int lane = tid & 63, wave = tid >> 6;          // 8 waves
  int quad = lane >> 4, l16 = lane & 15;
  int mBase = blockIdx.y * 256, nBase = blockIdx.x * 256;
  int wm = (wave >> 2) * 128, wn = (wave & 3) * 64;

  f32x4 acc[8][4];
#pragma unroll
  for (int mf = 0; mf < 8; mf++)
#pragma unroll
    for (int nf = 0; nf < 4; nf++) acc[mf][nf] = (f32x4){0.f, 0.f, 0.f, 0.f};

  // staging: wave w covers rows [32w, 32w+32) of the A and B tiles, as
  // 4 gl2lds of 8 rows (1 KiB) each. lane -> row r8 = lane>>3, global
  // chunk (lane&7)^r8 (pre-swizzle; LDS destination stays lane-linear).
  int r8 = lane >> 3;
  int csw = ((lane & 7) ^ r8) * 8;
  const f16* Ag = A + (size_t)(mBase + wave * 32 + r8) * Kd + csw;
  const f16* Bg = Bt + (size_t)(nBase + wave * 32 + r8) * Kd + csw;

  f16* lA0 = &sA[0][wave * 2048];
  f16* lA1 = &sA[1][wave * 2048];
  f16* lB0 = &sB[0][wave * 2048];
  f16* lB1 = &sB[1][wave * 2048];

#define STAGE_A(dst, t)                                                  \
  { _Pragma("unroll") for (int q = 0; q < 4; ++q)                        \
      gl2lds16(Ag + (size_t)(q * 8) * Kd + (size_t)(t) * 64, (dst) + q * 512); }
#define STAGE_B(dst, t)                                                  \
  { _Pragma("unroll") for (int q = 0; q < 4; ++q)                        \
      gl2lds16(Bg + (size_t)(q * 8) * Kd + (size_t)(t) * 64, (dst) + q * 512); }

  // fragment reads: global chunk cw for row r lives at LDS chunk cw^(r&7)
  int aRow = (wm + l16) * 64;
  int bRow = (wn + l16) * 64;
  int c0 = (quad ^ (l16 & 7)) * 8;   // k-step 0 (k in [quad*8, +8))
  int c1 = c0 ^ 32;                  // k-step 1 (chunk ^ 4)

  const int NT = Kd >> 6;   // 64-wide K-tiles
  STAGE_A(lA0, 0);
  STAGE_B(lB0, 0);

  const f16* sAc = &sA[0][0]; const f16* sAo = &sA[1][0];
  const f16* sBc = &sB[0][0]; const f16* sBo = &sB[1][0];
  f16* lAn = lA1; f16* lAo = lA0;
  f16* lBn = lB1; f16* lBo = lB0;

  for (int t = 0; t < NT; ++t) {
    if (t + 1 < NT) {
      STAGE_A(lAn, t + 1);
      // outstanding: A(t) 4 + B(t) 4 + A(t+1) 4 -> wait until only A(t+1)
      // remains in flight across the barrier.
      asm volatile("s_waitcnt vmcnt(4)" ::: "memory");
    } else {
      asm volatile("s_waitcnt vmcnt(0)" ::: "memory");
    }
    __builtin_amdgcn_s_barrier();
    __builtin_amdgcn_sched_barrier(0);   // pin ds_reads below the barrier

    f16x8 bf[4][2], af[4][2];
#pragma unroll
    for (int nf = 0; nf < 4; nf++) {
      bf[nf][0] = *(const f16x8*)&sBc[bRow + nf * 1024 + c0];
      bf[nf][1] = *(const f16x8*)&sBc[bRow + nf * 1024 + c1];
    }
#pragma unroll
    for (int mf = 0; mf < 4; mf++) {
      af[mf][0] = *(const f16x8*)&sAc[aRow + mf * 1024 + c0];
      af[mf][1] = *(const f16x8*)&sAc[aRow + mf * 1024 + c1];
    }
    __builtin_amdgcn_s_setprio(1);
#pragma unroll
    for (int mf = 0; mf < 4; mf++)
#pragma unroll
      for (int nf = 0; nf < 4; nf++) {
        acc[mf][nf] = __builtin_amdgcn_mfma_f32_16x16x32_f16(af[mf][0], bf[nf][0], acc[mf][nf], 0, 0, 0);
        acc[mf][nf] = __builtin_amdgcn_mfma_f32_16x16x32_f16(af[mf][1], bf[nf][1], acc[mf][nf], 0, 0, 0);
      }
    __builtin_amdgcn_s_setprio(0);

    if (t + 1 < NT) STAGE_B(lBn, t + 1);   // B latency hides under MFMA half 2

#pragma unroll
    for (int mf = 0; mf < 4; mf++) {
      af[mf][0] = *(const f16x8*)&sAc[aRow + 4096 + mf * 1024 + c0];
      af[mf][1] = *(const f16x8*)&sAc[aRow + 4096 + mf * 1024 + c1];
    }
    __builtin_amdgcn_s_setprio(1);
#pragma unroll
    for (int mf = 0; mf < 4; mf++)
#pragma unroll
      for (int nf = 0; nf < 4; nf++) {
        acc[mf + 4][nf] = __builtin_amdgcn_mfma_f32_16x16x32_f16(af[mf][0], bf[nf][0], acc[mf + 4][nf], 0, 0, 0);
        acc[mf + 4][nf] = __builtin_amdgcn_mfma_f32_16x16x32_f16(af[mf][1], bf[nf][1], acc[mf + 4][nf], 0, 0, 0);
      }
    __builtin_amdgcn_s_setprio(0);
    __builtin_amdgcn_sched_barrier(0);   // keep reads above the barrier
    __builtin_amdgcn_s_barrier();        // buf cur now dead -> restageable

    { const f16* tt;
      tt = sAc; sAc = sAo; sAo = tt;
      tt = sBc; sBc = sBo; sBo = tt; }
    { f16* tt;
      tt = lAn; lAn = lAo; lAo = tt;
      tt = lBn; lBn = lBo; lBo = tt; }
  }
#undef STAGE_A
#undef STAGE_B

#pragma unroll
  for (int mf = 0; mf < 8; mf++) {
    int row = mBase + wm + mf * 16 + quad * 4;
#pragma unroll
    for (int nf = 0; nf < 4; nf++) {
      int col = nBase + wn + nf * 16 + l16;
      OutT* Cp = C + (size_t)row * N + col;
#pragma unroll
      for (int r = 0; r < 4; r++) Cp[(size_t)r * N] = (OutT)acc[mf][nf][r];
    }
  }
}

// ---------------- sliding-tile flash attention (swapped-operand) ----------
// grid (T=32 tiles, NH=32, B=2), 256 threads = 4 waves, 32 q-rows each.
// Swapped QK^T: S^T = mfma(K-frag, Q-frag) -> lane l16 owns ONE q column.
// NEW this round (T14 async-STAGE + barrier diet):
//  * chunk c+1's K/V global loads issue into REGISTERS at the top of chunk
//    c (pinned by sched_barrier(0)); regs->LDS writes happen after the
//    post-PV barrier. HBM/L2 latency hides under QK^T+softmax+PV.
//  * softmax->PV __syncthreads dropped: P writes & pf reads are intra-wave
//    (wave w touches only sPt rows w*32..w*32+31; per-wave DS ops are
//    in-order). Barriers/chunk: 3 -> 2.
// sVt keeps col ^= (d&56) XOR swizzle; V staged in token pairs (f16x2).
__global__ __launch_bounds__(256) void attn_kernel(const f16* __restrict__ Q,
                                                   const f16* __restrict__ Kg,
                                                   const f16* __restrict__ V,
                                                   f16* __restrict__ O) {
  __shared__ f16 sK[64 * 72];
  __shared__ f16 sVt[64 * 72];    // V transposed: [d][k ^ (d&56)]
  __shared__ f16 sPt[128 * 72];   // P[q][k] packed; also Q staging buffer

  int t = blockIdx.x, h = blockIdx.y, b = blockIdx.z;
  int nth_i = t >> 2, ntw_i = t & 3;    // Ht=8, Wt=4
  int tid = threadIdx.x;
  int lane = tid & 63, wave = tid >> 6;
  int quad = lane >> 4, l16 = lane & 15;
  const size_t bstride = (size_t)N_SEQ * K_HID;
  const f16* Qb = Q + (size_t)b * bstride + h * 64;
  const f16* Kb = Kg + (size_t)b * bstride + h * 64;
  const f16* Vb = V + (size_t)b * bstride + h * 64;

  const float SC2 = 0.18033688f;   // (1/sqrt(64)) * log2(e)

  int cr = min(max(nth_i, 1), 7);   // clamped window center (tile units)
  int cc = min(max(ntw_i, 1), 3);

  // reg-staging geometry (fixed per thread): K rows klK & klK+32 at d-chunk
  // dcK; V token pair (k0V, k0V+1) at d-chunk dcV, swizzled col swcV.
  int klK = tid >> 3, dcK = (tid & 7) * 8;
  int k0V = (tid >> 3) * 2, dcV = (tid & 7) * 8;
  int swcV = k0V ^ dcV;
  float4 krg0, krg1; f16x8 v0r, v1r;

#define KV_LOAD(cx) {                                                         \
    int c_ = (cx);                                                            \
    int ti_ = cr - 1 + (c_ >> 2), tj_ = cc - 1 + ((c_ >> 1) & 1);             \
    int hb_ = (c_ & 1) * 64;                                                  \
    int kr_ = hb_ + klK;                                                      \
    int s_ = (ti_ * 8 + (kr_ >> 4)) * 64 + tj_ * 16 + (kr_ & 15);             \
    krg0 = *(const float4*)&Kb[(size_t)s_ * K_HID + dcK];                     \
    kr_ = hb_ + klK + 32;                                                     \
    s_ = (ti_ * 8 + (kr_ >> 4)) * 64 + tj_ * 16 + (kr_ & 15);                 \
    krg1 = *(const float4*)&Kb[(size_t)s_ * K_HID + dcK];                     \
    kr_ = hb_ + k0V;                                                          \
    s_ = (ti_ * 8 + (kr_ >> 4)) * 64 + tj_ * 16 + (kr_ & 15);                 \
    v0r = *(const f16x8*)&Vb[(size_t)s_ * K_HID + dcV];                       \
    kr_ = hb_ + k0V + 1;                                                      \
    s_ = (ti_ * 8 + (kr_ >> 4)) * 64 + tj_ * 16 + (kr_ & 15);                 \
    v1r = *(const f16x8*)&Vb[(size_t)s_ * K_HID + dcV];                       \
  }
#define KV_WRITE() {                                                          \
    *(float4*)&sK[klK * 72 + dcK] = krg0;                                     \
    *(float4*)&sK[(klK + 32) * 72 + dcK] = krg1;                              \
    _Pragma("unroll") for (int j = 0; j < 8; j++) {                           \
      f16x2 pv_; pv_[0] = v0r[j]; pv_[1] = v1r[j];                            \
      *(f16x2*)&sVt[(dcV + j) * 72 + swcV] = pv_;                             \
    }                                                                         \
  }

  // stage Q tile [128 x 64] via sPt; overlap chunk-0 K/V loads with it
  for (int i = tid; i < 1024; i += 256) {
    int qr = i >> 3, dc = (i & 7) * 8;
    int s = (nth_i * 8 + (qr >> 4)) * 64 + ntw_i * 16 + (qr & 15);
    *(float4*)&sPt[qr * 72 + dc] = *(const float4*)&Qb[(size_t)s * K_HID + dc];
  }
  KV_LOAD(0);
  __syncthreads();

  f16x8 qf[2][2];   // [q-subtile][d-half]; identical layout as A or B operand
#pragma unroll
  for (int qs = 0; qs < 2; qs++)
#pragma unroll
    for (int kk = 0; kk < 2; kk++)
      qf[qs][kk] = *(const f16x8*)&sPt[(wave * 32 + qs * 16 + l16) * 72 + kk * 32 + quad * 8];
  KV_WRITE();       // chunk-0 K/V into LDS (vmcnt wait auto-inserted)
  __syncthreads();

  f32x4 oacc[2][4];   // O^T: [qs][dt], col=l16=q, row=quad*4+r=d within dt
#pragma unroll
  for (int qs = 0; qs < 2; qs++)
#pragma unroll
    for (int dt = 0; dt < 4; dt++) oacc[qs][dt] = (f32x4){0.f, 0.f, 0.f, 0.f};
  float mrow[2] = {-1e30f, -1e30f};
  float lrow[2] = {0.f, 0.f};   // quad-partial rowsum; reduced at finalize

  for (int c = 0; c < 8; c++) {
    // issue next chunk's K/V loads early; latency hides under this chunk
    if (c < 7) KV_LOAD(c + 1);
    __builtin_amdgcn_sched_barrier(0);   // don't let the loads sink

    // S^T = K Q^T: sacc[qs][ks] col=l16=q, row=quad*4+r=k within ks block
    f32x4 sacc[2][4];
#pragma unroll
    for (int qs = 0; qs < 2; qs++)
#pragma unroll
      for (int ks = 0; ks < 4; ks++) sacc[qs][ks] = (f32x4){0.f, 0.f, 0.f, 0.f};
#pragma unroll
    for (int ks = 0; ks < 4; ks++) {
      f16x8 kf0 = *(const f16x8*)&sK[(ks * 16 + l16) * 72 + quad * 8];
      f16x8 kf1 = *(const f16x8*)&sK[(ks * 16 + l16) * 72 + 32 + quad * 8];
#pragma unroll
      for (int qs = 0; qs < 2; qs++) {
        sacc[qs][ks] = __builtin_amdgcn_mfma_f32_16x16x32_f16(kf0, qf[qs][0], sacc[qs][ks], 0, 0, 0);
        sacc[qs][ks] = __builtin_amdgcn_mfma_f32_16x16x32_f16(kf1, qf[qs][1], sacc[qs][ks], 0, 0, 0);
      }
    }

    // online softmax: lane owns q = l16; in-lane max over 16 + 2 cross-quad
#pragma unroll
    for (int qs = 0; qs < 2; qs++) {
      float mx = sacc[qs][0][0];
#pragma unroll
      for (int ks = 0; ks < 4; ks++)
#pragma unroll
        for (int r = 0; r < 4; r++) mx = fmaxf(mx, sacc[qs][ks][r]);
      mx = fmaxf(mx, __shfl_xor(mx, 16, 64));
      mx = fmaxf(mx, __shfl_xor(mx, 32, 64));
      mx *= SC2;
      float mold = mrow[qs];
      float mnew = fmaxf(mold, mx);
      mrow[qs] = mnew;
      float alpha = exp2f(mold - mnew);   // mold=-1e30 -> 0
      lrow[qs] *= alpha;
#pragma unroll
      for (int dt = 0; dt < 4; dt++)
#pragma unroll
        for (int r = 0; r < 4; r++) oacc[qs][dt][r] *= alpha;
      float ls = 0.f;
      int qrow = (wave * 32 + qs * 16 + l16) * 72;
#pragma unroll
      for (int ks = 0; ks < 4; ks++) {
        f16x4 pk;
#pragma unroll
        for (int r = 0; r < 4; r++) {
          float p = exp2f(sacc[qs][ks][r] * SC2 - mnew);
          ls += p;
          pk[r] = (f16)p;
        }
        *(f16x4*)&sPt[qrow + ks * 16 + quad * 4] = pk;   // P[q][k] b64 write
      }
      lrow[qs] += ls;
    }
    // NO __syncthreads here: P write -> pf read is intra-wave (own 32 rows),
    // and per-wave DS ops execute in order.

    // O^T += V^T P^T: A = V^T frag (rows d), B = P^T frag (cols q)
#pragma unroll
    for (int kk = 0; kk < 2; kk++) {
      f16x8 pf[2];
#pragma unroll
      for (int qs = 0; qs < 2; qs++)
        pf[qs] = *(const f16x8*)&sPt[(wave * 32 + qs * 16 + l16) * 72 + kk * 32 + quad * 8];
#pragma unroll
      for (int dt = 0; dt < 4; dt++) {
        int d = dt * 16 + l16;
        f16x8 vf = *(const f16x8*)&sVt[d * 72 + ((kk * 32 + quad * 8) ^ (d & 56))];
#pragma unroll
        for (int qs = 0; qs < 2; qs++)
          oacc[qs][dt] = __builtin_amdgcn_mfma_f32_16x16x32_f16(vf, pf[qs], oacc[qs][dt], 0, 0, 0);
      }
    }
    __syncthreads();   // all waves done reading sK/sVt of chunk c
    if (c < 7) {
      KV_WRITE();      // chunk c+1 regs -> LDS (vmcnt wait auto-inserted)
      __syncthreads();
    }
  }
#undef KV_LOAD
#undef KV_WRITE

  // finalize: cross-quad l reduce (2 shfl), divide, packed b64 stores
  f16* Ob = O + (size_t)b * bstride + h * 64;
#pragma unroll
  for (int qs = 0; qs < 2; qs++) {
    float l = lrow[qs];
    l += __shfl_xor(l, 16, 64);
    l += __shfl_xor(l, 32, 64);
    float inv = 1.0f / l;
    int q = wave * 32 + qs * 16 + l16;
    int s = (nth_i * 8 + (q >> 4)) * 64 + ntw_i * 16 + (q & 15);
#pragma unroll
    for (int dt = 0; dt < 4; dt++) {
      f16x4 ok;
#pragma unroll
      for (int r = 0; r < 4; r++) ok[r] = (f16)(oacc[qs][dt][r] * inv);
      *(f16x4*)&Ob[(size_t)s * K_HID + dt * 16 + quad * 4] = ok;
    }
  }
}

extern "C" void kernel_launch(void* const* d_in, const int* in_sizes, int n_in,
                              void* d_out, int out_size, void* d_ws, size_t ws_size,
                              hipStream_t stream) {
  const float* hs = (const float*)d_in[0];
  const float* Wq = (const float*)d_in[1];
  const float* Wk = (const float*)d_in[2];
  const float* Wv = (const float*)d_in[3];
  const float* Wo = (const float*)d_in[4];
  float* out = (float*)d_out;

  char* ws = (char*)d_ws;
  const size_t WELEM = (size_t)K_HID * K_HID;      // 4,194,304
  const size_t XELEM = (size_t)M_ROWS * K_HID;     // 16,777,216
  f16* WT = (f16*)ws;  ws += 4 * WELEM * sizeof(f16);  // WqT,WkT,WvT,WoT
  f16* Xh = (f16*)ws;  ws += XELEM * sizeof(f16);
  f16* Qb = (f16*)ws;  ws += XELEM * sizeof(f16);      // Q,K,V contiguous
  f16* Kb = (f16*)ws;  ws += XELEM * sizeof(f16);
  f16* Vb = (f16*)ws;  ws += XELEM * sizeof(f16);
  f16* Ob = (f16*)ws;  ws += XELEM * sizeof(f16);

  cvt_f32_to_f16<<<(int)(XELEM / (256 * 8)), 256, 0, stream>>>(hs, Xh, (int)XELEM);
  transpose_cvt<<<dim3(64, 64, 4), 256, 0, stream>>>(Wq, Wk, Wv, Wo, WT);
  gemm_bt<f16><<<dim3(8, 32, 3), 512, 0, stream>>>(Xh, WT, Qb, M_ROWS, K_HID, K_HID,
                                                   WELEM, XELEM);
  attn_kernel<<<dim3(32, 32, 2), 256, 0, stream>>>(Qb, Kb, Vb, Ob);
  gemm_bt<float><<<dim3(8, 32, 1), 512, 0, stream>>>(Ob, WT + 3 * WELEM, out,
                                                     M_ROWS, K_HID, K_HID, 0, 0);
}

// Round 7
// 522.314 us; speedup vs baseline: 1.0096x; 1.0096x over previous
//
#include <hip/hip_runtime.h>
#include <math.h>

typedef _Float16 f16;
typedef _Float16 f16x2 __attribute__((ext_vector_type(2)));
typedef _Float16 f16x4 __attribute__((ext_vector_type(4)));
typedef _Float16 f16x8 __attribute__((ext_vector_type(8)));
typedef float f32x4 __attribute__((ext_vector_type(4)));

#define K_HID 2048
#define N_SEQ 4096
#define N_BATCH 2
#define M_ROWS 8192   // B*S

// async global->LDS, 16B per lane. LDS dest must be WAVE-UNIFORM base;
// HW writes lane i at base + i*16 (lane-contiguous, no padding allowed).
__device__ __forceinline__ void gl2lds16(const f16* g, f16* l) {
  auto gp = (const __attribute__((address_space(1))) unsigned*)(unsigned long long)(uintptr_t)g;
  auto lp = (__attribute__((address_space(3))) unsigned*)(unsigned)(uintptr_t)l;
  __builtin_amdgcn_global_load_lds(gp, lp, 16, 0, 0);
}

// ---------------- f32 -> f16 conversion (8 elems/thread) ----------------
__global__ __launch_bounds__(256) void cvt_f32_to_f16(const float* __restrict__ x,
                                                      f16* __restrict__ y, int n) {
  int i = (blockIdx.x * 256 + threadIdx.x) * 8;
  if (i >= n) return;
  float4 a = *(const float4*)(x + i);
  float4 b = *(const float4*)(x + i + 4);
  f16x8 o;
  o[0] = (f16)a.x; o[1] = (f16)a.y; o[2] = (f16)a.z; o[3] = (f16)a.w;
  o[4] = (f16)b.x; o[5] = (f16)b.y; o[6] = (f16)b.z; o[7] = (f16)b.w;
  *(f16x8*)(y + i) = o;
}

// -------- weight transpose+convert: W[K][N] f32 -> Wt[N][K] f16 ----------
__global__ __launch_bounds__(256) void transpose_cvt(const float* __restrict__ W0,
                                                     const float* __restrict__ W1,
                                                     const float* __restrict__ W2,
                                                     const float* __restrict__ W3,
                                                     f16* __restrict__ WT) {
  const float* W = (blockIdx.z == 0) ? W0 : (blockIdx.z == 1) ? W1
                 : (blockIdx.z == 2) ? W2 : W3;
  f16* Wt = WT + (size_t)blockIdx.z * K_HID * K_HID;
  __shared__ float tile[32][33];
  int bx = blockIdx.x * 32;   // n base
  int by = blockIdx.y * 32;   // k base
  int x = threadIdx.x & 31;
  int y = threadIdx.x >> 5;   // 0..7
  for (int i = 0; i < 32; i += 8)
    tile[y + i][x] = W[(size_t)(by + y + i) * K_HID + bx + x];
  __syncthreads();
  for (int i = 0; i < 32; i += 8)
    Wt[(size_t)(bx + y + i) * K_HID + by + x] = (f16)tile[x][y + i];
}

// ---------------- GEMM: C[M][N] = A[M][K] * Bt[N][K]^T ----------------
// (round-2 schedule, unchanged since: 2 barriers/K-tile, counted vmcnt(4),
// 128B-row + 3-bit-XOR LDS layout, 0 bank conflicts, MfmaUtil 46.7%.)
// NEW (round 7): XCD-aware bijective block swizzle (T1/m204). HW
// round-robins flat blockIdx across the 8 XCDs, so the 8 x-blocks sharing
// an A row-panel land on 8 DIFFERENT per-XCD L2s -> every panel fetched
// ~8x from HBM (FETCH_SIZE 405MB vs 59MB unique) and the per-tile vmcnt
// wait eats ~900cy HBM latency. Remap so each XCD owns a CONTIGUOUS
// logical range (12 consecutive y-panels x all 8 x) -> panel reuse becomes
// XCD-local L2 hits (~200cy).
template <typename OutT>
__global__ __launch_bounds__(512, 2) void gemm_bt(const f16* __restrict__ A,
                                                  const f16* __restrict__ BtBase,
                                                  OutT* __restrict__ CBase,
                                                  int M, int N, int Kd,
                                                  size_t bzStride, size_t czStride) {
  int bx, by, bz;
  {
    const int gx = gridDim.x, gy = gridDim.y;
    const int nwg = gx * gy * gridDim.z;
    const int flat = blockIdx.x + gx * (blockIdx.y + gy * blockIdx.z);
    const int q = nwg >> 3, r = nwg & 7;
    const int xcd = flat & 7, pos = flat >> 3;
    const int lbid = (xcd < r) ? (xcd * (q + 1) + pos)
                               : (r * (q + 1) + (xcd - r) * q + pos);
    bx = lbid % gx;
    const int rem = lbid / gx;
    by = rem % gy;
    bz = rem / gy;
  }
  const f16* Bt = BtBase + bzStride * bz;
  OutT* C = CBase + czStride * bz;
  __shared__ f16 sA[2][256 * 64];   // 32 KiB per buffer
  __shared__ f16 sB[2][256 * 64];
  int tid = threadIdx.x;
  int lane = tid & 63, wave = tid >> 6;          // 8 waves
  int quad = lane >> 4, l16 = lane & 15;
  int mBase = by * 256, nBase = bx * 256;
  int wm = (wave >> 2) * 128, wn = (wave & 3) * 64;

  f32x4 acc[8][4];
#pragma unroll
  for (int mf = 0; mf < 8; mf++)
#pragma unroll
    for (int nf = 0; nf < 4; nf++) acc[mf][nf] = (f32x4){0.f, 0.f, 0.f, 0.f};

  // staging: wave w covers rows [32w, 32w+32) of the A and B tiles, as
  // 4 gl2lds of 8 rows (1 KiB) each. lane -> row r8 = lane>>3, global
  // chunk (lane&7)^r8 (pre-swizzle; LDS destination stays lane-linear).
  int r8 = lane >> 3;
  int csw = ((lane & 7) ^ r8) * 8;
  const f16* Ag = A + (size_t)(mBase + wave * 32 + r8) * Kd + csw;
  const f16* Bg = Bt + (size_t)(nBase + wave * 32 + r8) * Kd + csw;

  f16* lA0 = &sA[0][wave * 2048];
  f16* lA1 = &sA[1][wave * 2048];
  f16* lB0 = &sB[0][wave * 2048];
  f16* lB1 = &sB[1][wave * 2048];

#define STAGE_A(dst, t)                                                  \
  { _Pragma("unroll") for (int q = 0; q < 4; ++q)                        \
      gl2lds16(Ag + (size_t)(q * 8) * Kd + (size_t)(t) * 64, (dst) + q * 512); }
#define STAGE_B(dst, t)                                                  \
  { _Pragma("unroll") for (int q = 0; q < 4; ++q)                        \
      gl2lds16(Bg + (size_t)(q * 8) * Kd + (size_t)(t) * 64, (dst) + q * 512); }

  // fragment reads: global chunk cw for row r lives at LDS chunk cw^(r&7)
  int aRow = (wm + l16) * 64;
  int bRow = (wn + l16) * 64;
  int c0 = (quad ^ (l16 & 7)) * 8;   // k-step 0 (k in [quad*8, +8))
  int c1 = c0 ^ 32;                  // k-step 1 (chunk ^ 4)

  const int NT = Kd >> 6;   // 64-wide K-tiles
  STAGE_A(lA0, 0);
  STAGE_B(lB0, 0);

  const f16* sAc = &sA[0][0]; const f16* sAo = &sA[1][0];
  const f16* sBc = &sB[0][0]; const f16* sBo = &sB[1][0];
  f16* lAn = lA1; f16* lAo = lA0;
  f16* lBn = lB1; f16* lBo = lB0;

  for (int t = 0; t < NT; ++t) {
    if (t + 1 < NT) {
      STAGE_A(lAn, t + 1);
      // outstanding: A(t) 4 + B(t) 4 + A(t+1) 4 -> wait until only A(t+1)
      // remains in flight across the barrier.
      asm volatile("s_waitcnt vmcnt(4)" ::: "memory");
    } else {
      asm volatile("s_waitcnt vmcnt(0)" ::: "memory");
    }
    __builtin_amdgcn_s_barrier();
    __builtin_amdgcn_sched_barrier(0);   // pin ds_reads below the barrier

    f16x8 bf[4][2], af[4][2];
#pragma unroll
    for (int nf = 0; nf < 4; nf++) {
      bf[nf][0] = *(const f16x8*)&sBc[bRow + nf * 1024 + c0];
      bf[nf][1] = *(const f16x8*)&sBc[bRow + nf * 1024 + c1];
    }
#pragma unroll
    for (int mf = 0; mf < 4; mf++) {
      af[mf][0] = *(const f16x8*)&sAc[aRow + mf * 1024 + c0];
      af[mf][1] = *(const f16x8*)&sAc[aRow + mf * 1024 + c1];
    }
    __builtin_amdgcn_s_setprio(1);
#pragma unroll
    for (int mf = 0; mf < 4; mf++)
#pragma unroll
      for (int nf = 0; nf < 4; nf++) {
        acc[mf][nf] = __builtin_amdgcn_mfma_f32_16x16x32_f16(af[mf][0], bf[nf][0], acc[mf][nf], 0, 0, 0);
        acc[mf][nf] = __builtin_amdgcn_mfma_f32_16x16x32_f16(af[mf][1], bf[nf][1], acc[mf][nf], 0, 0, 0);
      }
    __builtin_amdgcn_s_setprio(0);

    if (t + 1 < NT) STAGE_B(lBn, t + 1);   // B latency hides under MFMA half 2

#pragma unroll
    for (int mf = 0; mf < 4; mf++) {
      af[mf][0] = *(const f16x8*)&sAc[aRow + 4096 + mf * 1024 + c0];
      af[mf][1] = *(const f16x8*)&sAc[aRow + 4096 + mf * 1024 + c1];
    }
    __builtin_amdgcn_s_setprio(1);
#pragma unroll
    for (int mf = 0; mf < 4; mf++)
#pragma unroll
      for (int nf = 0; nf < 4; nf++) {
        acc[mf + 4][nf] = __builtin_amdgcn_mfma_f32_16x16x32_f16(af[mf][0], bf[nf][0], acc[mf + 4][nf], 0, 0, 0);
        acc[mf + 4][nf] = __builtin_amdgcn_mfma_f32_16x16x32_f16(af[mf][1], bf[nf][1], acc[mf + 4][nf], 0, 0, 0);
      }
    __builtin_amdgcn_s_setprio(0);
    __builtin_amdgcn_sched_barrier(0);   // keep reads above the barrier
    __builtin_amdgcn_s_barrier();        // buf cur now dead -> restageable

    { const f16* tt;
      tt = sAc; sAc = sAo; sAo = tt;
      tt = sBc; sBc = sBo; sBo = tt; }
    { f16* tt;
      tt = lAn; lAn = lAo; lAo = tt;
      tt = lBn; lBn = lBo; lBo = tt; }
  }
#undef STAGE_A
#undef STAGE_B

#pragma unroll
  for (int mf = 0; mf < 8; mf++) {
    int row = mBase + wm + mf * 16 + quad * 4;
#pragma unroll
    for (int nf = 0; nf < 4; nf++) {
      int col = nBase + wn + nf * 16 + l16;
      OutT* Cp = C + (size_t)row * N + col;
#pragma unroll
      for (int r = 0; r < 4; r++) Cp[(size_t)r * N] = (OutT)acc[mf][nf][r];
    }
  }
}

// ---------------- sliding-tile flash attention (swapped-operand) ----------
// grid (T=32 tiles, NH=32, B=2), 256 threads = 4 waves, 32 q-rows each.
// Swapped QK^T: S^T = mfma(K-frag, Q-frag) -> lane l16 owns ONE q column.
// T14 async-STAGE (reg-staged K/V for chunk c+1 issued at top of chunk c),
// softmax->PV barrier dropped (intra-wave P rows). NEW (round 7): XCD
// swizzle so each XCD's L2 serves 8 heads' K/V (8.4MB) instead of all 32.
__global__ __launch_bounds__(256) void attn_kernel(const f16* __restrict__ Q,
                                                   const f16* __restrict__ Kg,
                                                   const f16* __restrict__ V,
                                                   f16* __restrict__ O) {
  __shared__ f16 sK[64 * 72];
  __shared__ f16 sVt[64 * 72];    // V transposed: [d][k ^ (d&56)]
  __shared__ f16 sPt[128 * 72];   // P[q][k] packed; also Q staging buffer

  int t, h, b;
  {
    const int flat = blockIdx.x + 32 * (blockIdx.y + 32 * blockIdx.z);
    const int q = 2048 >> 3;   // nwg = 2048, r = 0
    const int xcd = flat & 7, pos = flat >> 3;
    const int lbid = xcd * q + pos;
    t = lbid & 31; h = (lbid >> 5) & 31; b = lbid >> 10;
  }
  int nth_i = t >> 2, ntw_i = t & 3;    // Ht=8, Wt=4
  int tid = threadIdx.x;
  int lane = tid & 63, wave = tid >> 6;
  int quad = lane >> 4, l16 = lane & 15;
  const size_t bstride = (size_t)N_SEQ * K_HID;
  const f16* Qb = Q + (size_t)b * bstride + h * 64;
  const f16* Kb = Kg + (size_t)b * bstride + h * 64;
  const f16* Vb = V + (size_t)b * bstride + h * 64;

  const float SC2 = 0.18033688f;   // (1/sqrt(64)) * log2(e)

  int cr = min(max(nth_i, 1), 7);   // clamped window center (tile units)
  int cc = min(max(ntw_i, 1), 3);

  // reg-staging geometry (fixed per thread): K rows klK & klK+32 at d-chunk
  // dcK; V token pair (k0V, k0V+1) at d-chunk dcV, swizzled col swcV.
  int klK = tid >> 3, dcK = (tid & 7) * 8;
  int k0V = (tid >> 3) * 2, dcV = (tid & 7) * 8;
  int swcV = k0V ^ dcV;
  float4 krg0, krg1; f16x8 v0r, v1r;

#define KV_LOAD(cx) {                                                         \
    int c_ = (cx);                                                            \
    int ti_ = cr - 1 + (c_ >> 2), tj_ = cc - 1 + ((c_ >> 1) & 1);             \
    int hb_ = (c_ & 1) * 64;                                                  \
    int kr_ = hb_ + klK;                                                      \
    int s_ = (ti_ * 8 + (kr_ >> 4)) * 64 + tj_ * 16 + (kr_ & 15);             \
    krg0 = *(const float4*)&Kb[(size_t)s_ * K_HID + dcK];                     \
    kr_ = hb_ + klK + 32;                                                     \
    s_ = (ti_ * 8 + (kr_ >> 4)) * 64 + tj_ * 16 + (kr_ & 15);                 \
    krg1 = *(const float4*)&Kb[(size_t)s_ * K_HID + dcK];                     \
    kr_ = hb_ + k0V;                                                          \
    s_ = (ti_ * 8 + (kr_ >> 4)) * 64 + tj_ * 16 + (kr_ & 15);                 \
    v0r = *(const f16x8*)&Vb[(size_t)s_ * K_HID + dcV];                       \
    kr_ = hb_ + k0V + 1;                                                      \
    s_ = (ti_ * 8 + (kr_ >> 4)) * 64 + tj_ * 16 + (kr_ & 15);                 \
    v1r = *(const f16x8*)&Vb[(size_t)s_ * K_HID + dcV];                       \
  }
#define KV_WRITE() {                                                          \
    *(float4*)&sK[klK * 72 + dcK] = krg0;                                     \
    *(float4*)&sK[(klK + 32) * 72 + dcK] = krg1;                              \
    _Pragma("unroll") for (int j = 0; j < 8; j++) {                           \
      f16x2 pv_; pv_[0] = v0r[j]; pv_[1] = v1r[j];                            \
      *(f16x2*)&sVt[(dcV + j) * 72 + swcV] = pv_;                             \
    }                                                                         \
  }

  // stage Q tile [128 x 64] via sPt; overlap chunk-0 K/V loads with it
  for (int i = tid; i < 1024; i += 256) {
    int qr = i >> 3, dc = (i & 7) * 8;
    int s = (nth_i * 8 + (qr >> 4)) * 64 + ntw_i * 16 + (qr & 15);
    *(float4*)&sPt[qr * 72 + dc] = *(const float4*)&Qb[(size_t)s * K_HID + dc];
  }
  KV_LOAD(0);
  __syncthreads();

  f16x8 qf[2][2];   // [q-subtile][d-half]; identical layout as A or B operand
#pragma unroll
  for (int qs = 0; qs < 2; qs++)
#pragma unroll
    for (int kk = 0; kk < 2; kk++)
      qf[qs][kk] = *(const f16x8*)&sPt[(wave * 32 + qs * 16 + l16) * 72 + kk * 32 + quad * 8];
  KV_WRITE();       // chunk-0 K/V into LDS (vmcnt wait auto-inserted)
  __syncthreads();

  f32x4 oacc[2][4];   // O^T: [qs][dt], col=l16=q, row=quad*4+r=d within dt
#pragma unroll
  for (int qs = 0; qs < 2; qs++)
#pragma unroll
    for (int dt = 0; dt < 4; dt++) oacc[qs][dt] = (f32x4){0.f, 0.f, 0.f, 0.f};
  float mrow[2] = {-1e30f, -1e30f};
  float lrow[2] = {0.f, 0.f};   // quad-partial rowsum; reduced at finalize

  for (int c = 0; c < 8; c++) {
    // issue next chunk's K/V loads early; latency hides under this chunk
    if (c < 7) KV_LOAD(c + 1);
    __builtin_amdgcn_sched_barrier(0);   // don't let the loads sink

    // S^T = K Q^T: sacc[qs][ks] col=l16=q, row=quad*4+r=k within ks block
    f32x4 sacc[2][4];
#pragma unroll
    for (int qs = 0; qs < 2; qs++)
#pragma unroll
      for (int ks = 0; ks < 4; ks++) sacc[qs][ks] = (f32x4){0.f, 0.f, 0.f, 0.f};
#pragma unroll
    for (int ks = 0; ks < 4; ks++) {
      f16x8 kf0 = *(const f16x8*)&sK[(ks * 16 + l16) * 72 + quad * 8];
      f16x8 kf1 = *(const f16x8*)&sK[(ks * 16 + l16) * 72 + 32 + quad * 8];
#pragma unroll
      for (int qs = 0; qs < 2; qs++) {
        sacc[qs][ks] = __builtin_amdgcn_mfma_f32_16x16x32_f16(kf0, qf[qs][0], sacc[qs][ks], 0, 0, 0);
        sacc[qs][ks] = __builtin_amdgcn_mfma_f32_16x16x32_f16(kf1, qf[qs][1], sacc[qs][ks], 0, 0, 0);
      }
    }

    // online softmax: lane owns q = l16; in-lane max over 16 + 2 cross-quad
#pragma unroll
    for (int qs = 0; qs < 2; qs++) {
      float mx = sacc[qs][0][0];
#pragma unroll
      for (int ks = 0; ks < 4; ks++)
#pragma unroll
        for (int r = 0; r < 4; r++) mx = fmaxf(mx, sacc[qs][ks][r]);
      mx = fmaxf(mx, __shfl_xor(mx, 16, 64));
      mx = fmaxf(mx, __shfl_xor(mx, 32, 64));
      mx *= SC2;
      float mold = mrow[qs];
      float mnew = fmaxf(mold, mx);
      mrow[qs] = mnew;
      float alpha = exp2f(mold - mnew);   // mold=-1e30 -> 0
      lrow[qs] *= alpha;
#pragma unroll
      for (int dt = 0; dt < 4; dt++)
#pragma unroll
        for (int r = 0; r < 4; r++) oacc[qs][dt][r] *= alpha;
      float ls = 0.f;
      int qrow = (wave * 32 + qs * 16 + l16) * 72;
#pragma unroll
      for (int ks = 0; ks < 4; ks++) {
        f16x4 pk;
#pragma unroll
        for (int r = 0; r < 4; r++) {
          float p = exp2f(sacc[qs][ks][r] * SC2 - mnew);
          ls += p;
          pk[r] = (f16)p;
        }
        *(f16x4*)&sPt[qrow + ks * 16 + quad * 4] = pk;   // P[q][k] b64 write
      }
      lrow[qs] += ls;
    }
    // NO __syncthreads here: P write -> pf read is intra-wave (own 32 rows),
    // and per-wave DS ops execute in order.

    // O^T += V^T P^T: A = V^T frag (rows d), B = P^T frag (cols q)
#pragma unroll
    for (int kk = 0; kk < 2; kk++) {
      f16x8 pf[2];
#pragma unroll
      for (int qs = 0; qs < 2; qs++)
        pf[qs] = *(const f16x8*)&sPt[(wave * 32 + qs * 16 + l16) * 72 + kk * 32 + quad * 8];
#pragma unroll
      for (int dt = 0; dt < 4; dt++) {
        int d = dt * 16 + l16;
        f16x8 vf = *(const f16x8*)&sVt[d * 72 + ((kk * 32 + quad * 8) ^ (d & 56))];
#pragma unroll
        for (int qs = 0; qs < 2; qs++)
          oacc[qs][dt] = __builtin_amdgcn_mfma_f32_16x16x32_f16(vf, pf[qs], oacc[qs][dt], 0, 0, 0);
      }
    }
    __syncthreads();   // all waves done reading sK/sVt of chunk c
    if (c < 7) {
      KV_WRITE();      // chunk c+1 regs -> LDS (vmcnt wait auto-inserted)
      __syncthreads();
    }
  }
#undef KV_LOAD
#undef KV_WRITE

  // finalize: cross-quad l reduce (2 shfl), divide, packed b64 stores
  f16* Ob = O + (size_t)b * bstride + h * 64;
#pragma unroll
  for (int qs = 0; qs < 2; qs++) {
    float l = lrow[qs];
    l += __shfl_xor(l, 16, 64);
    l += __shfl_xor(l, 32, 64);
    float inv = 1.0f / l;
    int q = wave * 32 + qs * 16 + l16;
    int s = (nth_i * 8 + (q >> 4)) * 64 + ntw_i * 16 + (q & 15);
#pragma unroll
    for (int dt = 0; dt < 4; dt++) {
      f16x4 ok;
#pragma unroll
      for (int r = 0; r < 4; r++) ok[r] = (f16)(oacc[qs][dt][r] * inv);
      *(f16x4*)&Ob[(size_t)s * K_HID + dt * 16 + quad * 4] = ok;
    }
  }
}

extern "C" void kernel_launch(void* const* d_in, const int* in_sizes, int n_in,
                              void* d_out, int out_size, void* d_ws, size_t ws_size,
                              hipStream_t stream) {
  const float* hs = (const float*)d_in[0];
  const float* Wq = (const float*)d_in[1];
  const float* Wk = (const float*)d_in[2];
  const float* Wv = (const float*)d_in[3];
  const float* Wo = (const float*)d_in[4];
  float* out = (float*)d_out;

  char* ws = (char*)d_ws;
  const size_t WELEM = (size_t)K_HID * K_HID;      // 4,194,304
  const size_t XELEM = (size_t)M_ROWS * K_HID;     // 16,777,216
  f16* WT = (f16*)ws;  ws += 4 * WELEM * sizeof(f16);  // WqT,WkT,WvT,WoT
  f16* Xh = (f16*)ws;  ws += XELEM * sizeof(f16);
  f16* Qb = (f16*)ws;  ws += XELEM * sizeof(f16);      // Q,K,V contiguous
  f16* Kb = (f16*)ws;  ws += XELEM * sizeof(f16);
  f16* Vb = (f16*)ws;  ws += XELEM * sizeof(f16);
  f16* Ob = (f16*)ws;  ws += XELEM * sizeof(f16);

  cvt_f32_to_f16<<<(int)(XELEM / (256 * 8)), 256, 0, stream>>>(hs, Xh, (int)XELEM);
  transpose_cvt<<<dim3(64, 64, 4), 256, 0, stream>>>(Wq, Wk, Wv, Wo, WT);
  gemm_bt<f16><<<dim3(8, 32, 3), 512, 0, stream>>>(Xh, WT, Qb, M_ROWS, K_HID, K_HID,
                                                   WELEM, XELEM);
  attn_kernel<<<dim3(32, 32, 2), 256, 0, stream>>>(Qb, Kb, Vb, Ob);
  gemm_bt<float><<<dim3(8, 32, 1), 512, 0, stream>>>(Ob, WT + 3 * WELEM, out,
                                                     M_ROWS, K_HID, K_HID, 0, 0);
}

// Round 9
// 521.859 us; speedup vs baseline: 1.0105x; 1.0009x over previous
//
#include <hip/hip_runtime.h>
#include <math.h>

typedef _Float16 f16;
typedef _Float16 f16x2 __attribute__((ext_vector_type(2)));
typedef _Float16 f16x4 __attribute__((ext_vector_type(4)));
typedef _Float16 f16x8 __attribute__((ext_vector_type(8)));
typedef float f32x4 __attribute__((ext_vector_type(4)));

#define K_HID 2048
#define N_SEQ 4096
#define N_BATCH 2
#define M_ROWS 8192   // B*S

// async global->LDS, 16B per lane. LDS dest must be WAVE-UNIFORM base;
// HW writes lane i at base + i*16 (lane-contiguous, no padding allowed).
__device__ __forceinline__ void gl2lds16(const f16* g, f16* l) {
  auto gp = (const __attribute__((address_space(1))) unsigned*)(unsigned long long)(uintptr_t)g;
  auto lp = (__attribute__((address_space(3))) unsigned*)(unsigned)(uintptr_t)l;
  __builtin_amdgcn_global_load_lds(gp, lp, 16, 0, 0);
}

// ---------------- f32 -> f16 conversion (8 elems/thread) ----------------
__global__ __launch_bounds__(256) void cvt_f32_to_f16(const float* __restrict__ x,
                                                      f16* __restrict__ y, int n) {
  int i = (blockIdx.x * 256 + threadIdx.x) * 8;
  if (i >= n) return;
  float4 a = *(const float4*)(x + i);
  float4 b = *(const float4*)(x + i + 4);
  f16x8 o;
  o[0] = (f16)a.x; o[1] = (f16)a.y; o[2] = (f16)a.z; o[3] = (f16)a.w;
  o[4] = (f16)b.x; o[5] = (f16)b.y; o[6] = (f16)b.z; o[7] = (f16)b.w;
  *(f16x8*)(y + i) = o;
}

// -------- weight transpose+convert: W[K][N] f32 -> Wt[N][K] f16 ----------
__global__ __launch_bounds__(256) void transpose_cvt(const float* __restrict__ W0,
                                                     const float* __restrict__ W1,
                                                     const float* __restrict__ W2,
                                                     const float* __restrict__ W3,
                                                     f16* __restrict__ WT) {
  const float* W = (blockIdx.z == 0) ? W0 : (blockIdx.z == 1) ? W1
                 : (blockIdx.z == 2) ? W2 : W3;
  f16* Wt = WT + (size_t)blockIdx.z * K_HID * K_HID;
  __shared__ float tile[32][33];
  int bx = blockIdx.x * 32;   // n base
  int by = blockIdx.y * 32;   // k base
  int x = threadIdx.x & 31;
  int y = threadIdx.x >> 5;   // 0..7
  for (int i = 0; i < 32; i += 8)
    tile[y + i][x] = W[(size_t)(by + y + i) * K_HID + bx + x];
  __syncthreads();
  for (int i = 0; i < 32; i += 8)
    Wt[(size_t)(bx + y + i) * K_HID + by + x] = (f16)tile[x][y + i];
}

// ---------------- GEMM: C[M][N] = A[M][K] * Bt[N][K]^T ----------------
// 256x256 tile, BK=64, 512 threads = 8 waves (2M x 4N), per-wave 128x64 out.
// 2 barriers/K-tile, counted vmcnt, 128B-row + 3-bit-XOR LDS (0 conflicts),
// XCD-aware bijective block swizzle (r7: FETCH 405->147MB).
// Round 8 (resubmitted; r8 bench was an infra failure): single-burst
// schedule. Round-7 showed the stall is on-CU: 192 ds_read_b128/CU/tile
// ~= 2300cy of DS-engine time, and the old 2-cluster loop issued the 2nd
// af-batch AFTER the 1st MFMA cluster -> cluster 2 ate the DS latency
// serially, with STG_B splitting the clusters. Now: stage BOTH A(t+1) and
// B(t+1) at tile top (vmcnt(8) keeps all 8 in flight across the barrier,
// a full ~4800cy of slack), issue ALL 24 fragment reads up-front (bf first
// - consumed earliest per mf-row), one 64-MFMA setprio cluster. DS engine
// streams reads DURING the MFMAs (compiler emits fine lgkmcnt, r109).
// VGPR ~230 expected; alarm = 256+scratch.
template <typename OutT>
__global__ __launch_bounds__(512, 2) void gemm_bt(const f16* __restrict__ A,
                                                  const f16* __restrict__ BtBase,
                                                  OutT* __restrict__ CBase,
                                                  int M, int N, int Kd,
                                                  size_t bzStride, size_t czStride) {
  int bx, by, bz;
  {
    const int gx = gridDim.x, gy = gridDim.y;
    const int nwg = gx * gy * gridDim.z;
    const int flat = blockIdx.x + gx * (blockIdx.y + gy * blockIdx.z);
    const int q = nwg >> 3, r = nwg & 7;
    const int xcd = flat & 7, pos = flat >> 3;
    const int lbid = (xcd < r) ? (xcd * (q + 1) + pos)
                               : (r * (q + 1) + (xcd - r) * q + pos);
    bx = lbid % gx;
    const int rem = lbid / gx;
    by = rem % gy;
    bz = rem / gy;
  }
  const f16* Bt = BtBase + bzStride * bz;
  OutT* C = CBase + czStride * bz;
  __shared__ f16 sA[2][256 * 64];   // 32 KiB per buffer
  __shared__ f16 sB[2][256 * 64];
  int tid = threadIdx.x;
  int lane = tid & 63, wave = tid >> 6;          // 8 waves
  int quad = lane >> 4, l16 = lane & 15;
  int mBase = by * 256, nBase = bx * 256;
  int wm = (wave >> 2) * 128, wn = (wave & 3) * 64;

  f32x4 acc[8][4];
#pragma unroll
  for (int mf = 0; mf < 8; mf++)
#pragma unroll
    for (int nf = 0; nf < 4; nf++) acc[mf][nf] = (f32x4){0.f, 0.f, 0.f, 0.f};

  // staging: wave w covers rows [32w, 32w+32) of the A and B tiles, as
  // 4 gl2lds of 8 rows (1 KiB) each. lane -> row r8 = lane>>3, global
  // chunk (lane&7)^r8 (pre-swizzle; LDS destination stays lane-linear).
  int r8 = lane >> 3;
  int csw = ((lane & 7) ^ r8) * 8;
  const f16* Ag = A + (size_t)(mBase + wave * 32 + r8) * Kd + csw;
  const f16* Bg = Bt + (size_t)(nBase + wave * 32 + r8) * Kd + csw;

  f16* lA0 = &sA[0][wave * 2048];
  f16* lA1 = &sA[1][wave * 2048];
  f16* lB0 = &sB[0][wave * 2048];
  f16* lB1 = &sB[1][wave * 2048];

#define STAGE_A(dst, t)                                                  \
  { _Pragma("unroll") for (int q = 0; q < 4; ++q)                        \
      gl2lds16(Ag + (size_t)(q * 8) * Kd + (size_t)(t) * 64, (dst) + q * 512); }
#define STAGE_B(dst, t)                                                  \
  { _Pragma("unroll") for (int q = 0; q < 4; ++q)                        \
      gl2lds16(Bg + (size_t)(q * 8) * Kd + (size_t)(t) * 64, (dst) + q * 512); }

  // fragment reads: global chunk cw for row r lives at LDS chunk cw^(r&7)
  int aRow = (wm + l16) * 64;
  int bRow = (wn + l16) * 64;
  int c0 = (quad ^ (l16 & 7)) * 8;   // k-step 0 (k in [quad*8, +8))
  int c1 = c0 ^ 32;                  // k-step 1 (chunk ^ 4)

  const int NT = Kd >> 6;   // 64-wide K-tiles
  STAGE_A(lA0, 0);
  STAGE_B(lB0, 0);

  const f16* sAc = &sA[0][0]; const f16* sAo = &sA[1][0];
  const f16* sBc = &sB[0][0]; const f16* sBo = &sB[1][0];
  f16* lAn = lA1; f16* lAo = lA0;
  f16* lBn = lB1; f16* lBo = lB0;

  for (int t = 0; t < NT; ++t) {
    if (t + 1 < NT) {
      STAGE_A(lAn, t + 1);
      STAGE_B(lBn, t + 1);
      // outstanding: A(t)+B(t) [oldest 8] + A(t+1)+B(t+1) [new 8] ->
      // retire tile t's; keep all 8 of t+1 in flight across the barrier
      // (a full tile ~4800cy of latency slack).
      asm volatile("s_waitcnt vmcnt(8)" ::: "memory");
    } else {
      asm volatile("s_waitcnt vmcnt(0)" ::: "memory");
    }
    __builtin_amdgcn_s_barrier();
    __builtin_amdgcn_sched_barrier(0);   // pin ds_reads below the barrier

    // ALL 24 fragment reads up-front; DS engine streams them while the
    // MFMA cluster consumes in order (fine-grained lgkmcnt by compiler).
    f16x8 af[8][2], bf[4][2];
#pragma unroll
    for (int nf = 0; nf < 4; nf++) {
      bf[nf][0] = *(const f16x8*)&sBc[bRow + nf * 1024 + c0];
      bf[nf][1] = *(const f16x8*)&sBc[bRow + nf * 1024 + c1];
    }
#pragma unroll
    for (int mf = 0; mf < 8; mf++) {
      af[mf][0] = *(const f16x8*)&sAc[aRow + mf * 1024 + c0];
      af[mf][1] = *(const f16x8*)&sAc[aRow + mf * 1024 + c1];
    }
    __builtin_amdgcn_s_setprio(1);
#pragma unroll
    for (int mf = 0; mf < 8; mf++)
#pragma unroll
      for (int nf = 0; nf < 4; nf++) {
        acc[mf][nf] = __builtin_amdgcn_mfma_f32_16x16x32_f16(af[mf][0], bf[nf][0], acc[mf][nf], 0, 0, 0);
        acc[mf][nf] = __builtin_amdgcn_mfma_f32_16x16x32_f16(af[mf][1], bf[nf][1], acc[mf][nf], 0, 0, 0);
      }
    __builtin_amdgcn_s_setprio(0);
    __builtin_amdgcn_sched_barrier(0);   // keep reads above the barrier
    __builtin_amdgcn_s_barrier();        // buf cur now dead -> restageable

    { const f16* tt;
      tt = sAc; sAc = sAo; sAo = tt;
      tt = sBc; sBc = sBo; sBo = tt; }
    { f16* tt;
      tt = lAn; lAn = lAo; lAo = tt;
      tt = lBn; lBn = lBo; lBo = tt; }
  }
#undef STAGE_A
#undef STAGE_B

#pragma unroll
  for (int mf = 0; mf < 8; mf++) {
    int row = mBase + wm + mf * 16 + quad * 4;
#pragma unroll
    for (int nf = 0; nf < 4; nf++) {
      int col = nBase + wn + nf * 16 + l16;
      OutT* Cp = C + (size_t)row * N + col;
#pragma unroll
      for (int r = 0; r < 4; r++) Cp[(size_t)r * N] = (OutT)acc[mf][nf][r];
    }
  }
}

// ---------------- sliding-tile flash attention (swapped-operand) ----------
// grid (T=32 tiles, NH=32, B=2), 256 threads = 4 waves, 32 q-rows each.
// Swapped QK^T: S^T = mfma(K-frag, Q-frag) -> lane l16 owns ONE q column.
// T14 async-STAGE (reg-staged K/V for chunk c+1 issued at top of chunk c),
// softmax->PV barrier dropped (intra-wave P rows). XCD swizzle: each XCD's
// L2 serves 8 heads' K/V (8.4MB) instead of all 32.
__global__ __launch_bounds__(256) void attn_kernel(const f16* __restrict__ Q,
                                                   const f16* __restrict__ Kg,
                                                   const f16* __restrict__ V,
                                                   f16* __restrict__ O) {
  __shared__ f16 sK[64 * 72];
  __shared__ f16 sVt[64 * 72];    // V transposed: [d][k ^ (d&56)]
  __shared__ f16 sPt[128 * 72];   // P[q][k] packed; also Q staging buffer

  int t, h, b;
  {
    const int flat = blockIdx.x + 32 * (blockIdx.y + 32 * blockIdx.z);
    const int q = 2048 >> 3;   // nwg = 2048, r = 0
    const int xcd = flat & 7, pos = flat >> 3;
    const int lbid = xcd * q + pos;
    t = lbid & 31; h = (lbid >> 5) & 31; b = lbid >> 10;
  }
  int nth_i = t >> 2, ntw_i = t & 3;    // Ht=8, Wt=4
  int tid = threadIdx.x;
  int lane = tid & 63, wave = tid >> 6;
  int quad = lane >> 4, l16 = lane & 15;
  const size_t bstride = (size_t)N_SEQ * K_HID;
  const f16* Qb = Q + (size_t)b * bstride + h * 64;
  const f16* Kb = Kg + (size_t)b * bstride + h * 64;
  const f16* Vb = V + (size_t)b * bstride + h * 64;

  const float SC2 = 0.18033688f;   // (1/sqrt(64)) * log2(e)

  int cr = min(max(nth_i, 1), 7);   // clamped window center (tile units)
  int cc = min(max(ntw_i, 1), 3);

  // reg-staging geometry (fixed per thread): K rows klK & klK+32 at d-chunk
  // dcK; V token pair (k0V, k0V+1) at d-chunk dcV, swizzled col swcV.
  int klK = tid >> 3, dcK = (tid & 7) * 8;
  int k0V = (tid >> 3) * 2, dcV = (tid & 7) * 8;
  int swcV = k0V ^ dcV;
  float4 krg0, krg1; f16x8 v0r, v1r;

#define KV_LOAD(cx) {                                                         \
    int c_ = (cx);                                                            \
    int ti_ = cr - 1 + (c_ >> 2), tj_ = cc - 1 + ((c_ >> 1) & 1);             \
    int hb_ = (c_ & 1) * 64;                                                  \
    int kr_ = hb_ + klK;                                                      \
    int s_ = (ti_ * 8 + (kr_ >> 4)) * 64 + tj_ * 16 + (kr_ & 15);             \
    krg0 = *(const float4*)&Kb[(size_t)s_ * K_HID + dcK];                     \
    kr_ = hb_ + klK + 32;                                                     \
    s_ = (ti_ * 8 + (kr_ >> 4)) * 64 + tj_ * 16 + (kr_ & 15);                 \
    krg1 = *(const float4*)&Kb[(size_t)s_ * K_HID + dcK];                     \
    kr_ = hb_ + k0V;                                                          \
    s_ = (ti_ * 8 + (kr_ >> 4)) * 64 + tj_ * 16 + (kr_ & 15);                 \
    v0r = *(const f16x8*)&Vb[(size_t)s_ * K_HID + dcV];                       \
    kr_ = hb_ + k0V + 1;                                                      \
    s_ = (ti_ * 8 + (kr_ >> 4)) * 64 + tj_ * 16 + (kr_ & 15);                 \
    v1r = *(const f16x8*)&Vb[(size_t)s_ * K_HID + dcV];                       \
  }
#define KV_WRITE() {                                                          \
    *(float4*)&sK[klK * 72 + dcK] = krg0;                                     \
    *(float4*)&sK[(klK + 32) * 72 + dcK] = krg1;                              \
    _Pragma("unroll") for (int j = 0; j < 8; j++) {                           \
      f16x2 pv_; pv_[0] = v0r[j]; pv_[1] = v1r[j];                            \
      *(f16x2*)&sVt[(dcV + j) * 72 + swcV] = pv_;                             \
    }                                                                         \
  }

  // stage Q tile [128 x 64] via sPt; overlap chunk-0 K/V loads with it
  for (int i = tid; i < 1024; i += 256) {
    int qr = i >> 3, dc = (i & 7) * 8;
    int s = (nth_i * 8 + (qr >> 4)) * 64 + ntw_i * 16 + (qr & 15);
    *(float4*)&sPt[qr * 72 + dc] = *(const float4*)&Qb[(size_t)s * K_HID + dc];
  }
  KV_LOAD(0);
  __syncthreads();

  f16x8 qf[2][2];   // [q-subtile][d-half]; identical layout as A or B operand
#pragma unroll
  for (int qs = 0; qs < 2; qs++)
#pragma unroll
    for (int kk = 0; kk < 2; kk++)
      qf[qs][kk] = *(const f16x8*)&sPt[(wave * 32 + qs * 16 + l16) * 72 + kk * 32 + quad * 8];
  KV_WRITE();       // chunk-0 K/V into LDS (vmcnt wait auto-inserted)
  __syncthreads();

  f32x4 oacc[2][4];   // O^T: [qs][dt], col=l16=q, row=quad*4+r=d within dt
#pragma unroll
  for (int qs = 0; qs < 2; qs++)
#pragma unroll
    for (int dt = 0; dt < 4; dt++) oacc[qs][dt] = (f32x4){0.f, 0.f, 0.f, 0.f};
  float mrow[2] = {-1e30f, -1e30f};
  float lrow[2] = {0.f, 0.f};   // quad-partial rowsum; reduced at finalize

  for (int c = 0; c < 8; c++) {
    // issue next chunk's K/V loads early; latency hides under this chunk
    if (c < 7) KV_LOAD(c + 1);
    __builtin_amdgcn_sched_barrier(0);   // don't let the loads sink

    // S^T = K Q^T: sacc[qs][ks] col=l16=q, row=quad*4+r=k within ks block
    f32x4 sacc[2][4];
#pragma unroll
    for (int qs = 0; qs < 2; qs++)
#pragma unroll
      for (int ks = 0; ks < 4; ks++) sacc[qs][ks] = (f32x4){0.f, 0.f, 0.f, 0.f};
#pragma unroll
    for (int ks = 0; ks < 4; ks++) {
      f16x8 kf0 = *(const f16x8*)&sK[(ks * 16 + l16) * 72 + quad * 8];
      f16x8 kf1 = *(const f16x8*)&sK[(ks * 16 + l16) * 72 + 32 + quad * 8];
#pragma unroll
      for (int qs = 0; qs < 2; qs++) {
        sacc[qs][ks] = __builtin_amdgcn_mfma_f32_16x16x32_f16(kf0, qf[qs][0], sacc[qs][ks], 0, 0, 0);
        sacc[qs][ks] = __builtin_amdgcn_mfma_f32_16x16x32_f16(kf1, qf[qs][1], sacc[qs][ks], 0, 0, 0);
      }
    }

    // online softmax: lane owns q = l16; in-lane max over 16 + 2 cross-quad
#pragma unroll
    for (int qs = 0; qs < 2; qs++) {
      float mx = sacc[qs][0][0];
#pragma unroll
      for (int ks = 0; ks < 4; ks++)
#pragma unroll
        for (int r = 0; r < 4; r++) mx = fmaxf(mx, sacc[qs][ks][r]);
      mx = fmaxf(mx, __shfl_xor(mx, 16, 64));
      mx = fmaxf(mx, __shfl_xor(mx, 32, 64));
      mx *= SC2;
      float mold = mrow[qs];
      float mnew = fmaxf(mold, mx);
      mrow[qs] = mnew;
      float alpha = exp2f(mold - mnew);   // mold=-1e30 -> 0
      lrow[qs] *= alpha;
#pragma unroll
      for (int dt = 0; dt < 4; dt++)
#pragma unroll
        for (int r = 0; r < 4; r++) oacc[qs][dt][r] *= alpha;
      float ls = 0.f;
      int qrow = (wave * 32 + qs * 16 + l16) * 72;
#pragma unroll
      for (int ks = 0; ks < 4; ks++) {
        f16x4 pk;
#pragma unroll
        for (int r = 0; r < 4; r++) {
          float p = exp2f(sacc[qs][ks][r] * SC2 - mnew);
          ls += p;
          pk[r] = (f16)p;
        }
        *(f16x4*)&sPt[qrow + ks * 16 + quad * 4] = pk;   // P[q][k] b64 write
      }
      lrow[qs] += ls;
    }
    // NO __syncthreads here: P write -> pf read is intra-wave (own 32 rows),
    // and per-wave DS ops execute in order.

    // O^T += V^T P^T: A = V^T frag (rows d), B = P^T frag (cols q)
#pragma unroll
    for (int kk = 0; kk < 2; kk++) {
      f16x8 pf[2];
#pragma unroll
      for (int qs = 0; qs < 2; qs++)
        pf[qs] = *(const f16x8*)&sPt[(wave * 32 + qs * 16 + l16) * 72 + kk * 32 + quad * 8];
#pragma unroll
      for (int dt = 0; dt < 4; dt++) {
        int d = dt * 16 + l16;
        f16x8 vf = *(const f16x8*)&sVt[d * 72 + ((kk * 32 + quad * 8) ^ (d & 56))];
#pragma unroll
        for (int qs = 0; qs < 2; qs++)
          oacc[qs][dt] = __builtin_amdgcn_mfma_f32_16x16x32_f16(vf, pf[qs], oacc[qs][dt], 0, 0, 0);
      }
    }
    __syncthreads();   // all waves done reading sK/sVt of chunk c
    if (c < 7) {
      KV_WRITE();      // chunk c+1 regs -> LDS (vmcnt wait auto-inserted)
      __syncthreads();
    }
  }
#undef KV_LOAD
#undef KV_WRITE

  // finalize: cross-quad l reduce (2 shfl), divide, packed b64 stores
  f16* Ob = O + (size_t)b * bstride + h * 64;
#pragma unroll
  for (int qs = 0; qs < 2; qs++) {
    float l = lrow[qs];
    l += __shfl_xor(l, 16, 64);
    l += __shfl_xor(l, 32, 64);
    float inv = 1.0f / l;
    int q = wave * 32 + qs * 16 + l16;
    int s = (nth_i * 8 + (q >> 4)) * 64 + ntw_i * 16 + (q & 15);
#pragma unroll
    for (int dt = 0; dt < 4; dt++) {
      f16x4 ok;
#pragma unroll
      for (int r = 0; r < 4; r++) ok[r] = (f16)(oacc[qs][dt][r] * inv);
      *(f16x4*)&Ob[(size_t)s * K_HID + dt * 16 + quad * 4] = ok;
    }
  }
}

extern "C" void kernel_launch(void* const* d_in, const int* in_sizes, int n_in,
                              void* d_out, int out_size, void* d_ws, size_t ws_size,
                              hipStream_t stream) {
  const float* hs = (const float*)d_in[0];
  const float* Wq = (const float*)d_in[1];
  const float* Wk = (const float*)d_in[2];
  const float* Wv = (const float*)d_in[3];
  const float* Wo = (const float*)d_in[4];
  float* out = (float*)d_out;

  char* ws = (char*)d_ws;
  const size_t WELEM = (size_t)K_HID * K_HID;      // 4,194,304
  const size_t XELEM = (size_t)M_ROWS * K_HID;     // 16,777,216
  f16* WT = (f16*)ws;  ws += 4 * WELEM * sizeof(f16);  // WqT,WkT,WvT,WoT
  f16* Xh = (f16*)ws;  ws += XELEM * sizeof(f16);
  f16* Qb = (f16*)ws;  ws += XELEM * sizeof(f16);      // Q,K,V contiguous
  f16* Kb = (f16*)ws;  ws += XELEM * sizeof(f16);
  f16* Vb = (f16*)ws;  ws += XELEM * sizeof(f16);
  f16* Ob = (f16*)ws;  ws += XELEM * sizeof(f16);

  cvt_f32_to_f16<<<(int)(XELEM / (256 * 8)), 256, 0, stream>>>(hs, Xh, (int)XELEM);
  transpose_cvt<<<dim3(64, 64, 4), 256, 0, stream>>>(Wq, Wk, Wv, Wo, WT);
  gemm_bt<f16><<<dim3(8, 32, 3), 512, 0, stream>>>(Xh, WT, Qb, M_ROWS, K_HID, K_HID,
                                                   WELEM, XELEM);
  attn_kernel<<<dim3(32, 32, 2), 256, 0, stream>>>(Qb, Kb, Vb, Ob);
  gemm_bt<float><<<dim3(8, 32, 1), 512, 0, stream>>>(Ob, WT + 3 * WELEM, out,
                                                     M_ROWS, K_HID, K_HID, 0, 0);
}